// Round 13
// baseline (163.580 us; speedup 1.0000x reference)
//
#include <hip/hip_runtime.h>
#include <math.h>

constexpr int H = 2048;
constexpr int W = 4096;
constexpr int RS = W * 3;   // floats per image row

__device__ __forceinline__ float k_inner(float t) {   // t in [0,1]
    return fmaf(fmaf(1.5f, t, -2.5f), t * t, 1.0f);
}
__device__ __forceinline__ float k_outer(float t) {   // t in [1,2]
    return fmaf(fmaf(fmaf(-0.5f, t, 2.5f), t, -4.0f), t, 2.0f);
}
__device__ __forceinline__ float cubic_w(float t) {
    float at = fabsf(t);
    if (at <= 1.0f) return k_inner(at);
    if (at < 2.0f)  return k_outer(at);
    return 0.0f;
}

// general clamped 16-tap gather (exec-masked patch path, ~1% of lanes)
__device__ __noinline__ void gather_px(const float* __restrict__ img,
                                       int iy, int ix,
                                       float fy, float fx,
                                       float& o0, float& o1, float& o2) {
    float wy[4] = {k_outer(1.f + fy), k_inner(fy), k_inner(1.f - fy), k_outer(2.f - fy)};
    float wx[4] = {k_outer(1.f + fx), k_inner(fx), k_inner(1.f - fx), k_outer(2.f - fx)};
    o0 = 0.f; o1 = 0.f; o2 = 0.f;
#pragma unroll
    for (int a = 0; a < 4; ++a) {
        int ty = iy + a - 1;
        ty = ty < 0 ? 0 : (ty > H - 1 ? H - 1 : ty);
        int rowoff = ty * RS;
        float ay = wy[a];
#pragma unroll
        for (int b = 0; b < 4; ++b) {
            int tx = ix + b - 1;
            tx = tx < 0 ? 0 : (tx > W - 1 ? W - 1 : tx);
            float wgt = ay * wx[b];
            const float* p = img + rowoff + tx * 3;
            o0 += wgt * p[0];
            o1 += wgt * p[1];
            o2 += wgt * p[2];
        }
    }
}

// per-row 4-tap x 3-channel dot from 3 float4 (12 contiguous floats)
#define ROWDOT(va, vb, vc, wxA, wxB, wxC, wxD, T0, T1, T2)                         \
    T0 = fmaf(wxA, va.x, fmaf(wxB, va.w, fmaf(wxC, vb.z, wxD * vc.y)));            \
    T1 = fmaf(wxA, va.y, fmaf(wxB, vb.x, fmaf(wxC, vb.w, wxD * vc.z)));            \
    T2 = fmaf(wxA, va.z, fmaf(wxB, vb.y, fmaf(wxC, vc.x, wxD * vc.w)));

// Block region: 64 wide x 32 tall, in 4 x-iterations of 16 px.
// Lane: xi = lane&15 (col), gi = lane>>4; thread owns the vertical px pair
// (h0, w), (h0+1, w) with h0 = y0 + (wave*4+gi)*2.
__global__ __launch_bounds__(256)
void elastic_warp_kernel(const float* __restrict__ img,
                         const float* __restrict__ dctrl,  // (2,3,3) unscaled
                         float* __restrict__ out) {
    int x0r = blockIdx.x << 6;    // 64-px x-region
    int y0  = blockIdx.y << 5;    // 32-px y-band

    int t = threadIdx.x;
    int lane = t & 63;
    int wave = t >> 6;
    int xi = lane & 15;
    int gi = lane >> 4;
    int r0 = ((wave << 2) + gi) << 1;   // even row within band, 0..30

    // ---- per-band-row uniform: cy = 5 * (by^T . D), 32 rows ----
    __shared__ float s_cy[32][6];
    if (t < 32) {
        int hh = y0 + t;
        float u = (float)(2 * hh) / (float)(H - 1);
        float i0 = floorf(u);
        float by0 = 0.f, by1 = 0.f, by2 = 0.f;
#pragma unroll
        for (int k = -1; k < 3; ++k) {
            float tap = i0 + (float)k;
            float wt = cubic_w(u - tap);
            int tc = (int)tap;
            tc = tc < 0 ? 0 : (tc > 2 ? 2 : tc);
            if (tc == 0) by0 += wt; else if (tc == 1) by1 += wt; else by2 += wt;
        }
#pragma unroll
        for (int x = 0; x < 3; ++x) {
            s_cy[t][x]     = 5.0f * (by0 * dctrl[x]     + by1 * dctrl[3 + x]  + by2 * dctrl[6 + x]);
            s_cy[t][3 + x] = 5.0f * (by0 * dctrl[9 + x] + by1 * dctrl[12 + x] + by2 * dctrl[15 + x]);
        }
    }
    __syncthreads();

    int h0 = y0 + r0;
    float cyA0 = s_cy[r0][0], cyA1 = s_cy[r0][1], cyA2 = s_cy[r0][2];
    float cyA3 = s_cy[r0][3], cyA4 = s_cy[r0][4], cyA5 = s_cy[r0][5];
    float cyB0 = s_cy[r0+1][0], cyB1 = s_cy[r0+1][1], cyB2 = s_cy[r0+1][2];
    float cyB3 = s_cy[r0+1][3], cyB4 = s_cy[r0+1][4], cyB5 = s_cy[r0+1][5];
    int rowbase0 = (h0 * W) * 3;

#pragma unroll
    for (int it = 0; it < 4; ++it) {
        int w = x0r + (it << 4) + xi;

        // ---- shared bx (same w for both px of the pair) ----
        float u = (float)w * (2.0f / 4095.0f);
        bool hiu = u >= 1.0f;
        float s = u - (hiu ? 1.0f : 0.0f);
        float o1 = k_outer(1.0f + s);
        float is = k_inner(s);
        float i1 = k_inner(1.0f - s);
        float o2 = k_outer(2.0f - s);
        float bx0 = hiu ? o1 : (o1 + is);
        float bx1 = hiu ? is : i1;
        float bx2 = hiu ? (i1 + o2) : o2;

        float d0a = cyA0 * bx0 + cyA1 * bx1 + cyA2 * bx2;
        float d1a = cyA3 * bx0 + cyA4 * bx1 + cyA5 * bx2;
        float d0b = cyB0 * bx0 + cyB1 * bx1 + cyB2 * bx2;
        float d1b = cyB3 * bx0 + cyB4 * bx1 + cyB5 * bx2;

        float yy0 = (float)h0 + d0a,        xx0 = (float)w + d1a;
        float yy1 = (float)(h0 + 1) + d0b,  xx1 = (float)w + d1b;
        float fly0 = floorf(yy0), flx0 = floorf(xx0);
        float fly1 = floorf(yy1), flx1 = floorf(xx1);
        float fy0 = yy0 - fly0, fx0 = xx0 - flx0;
        float fy1 = yy1 - fly1, fx1 = xx1 - flx1;
        int iy0 = (int)fly0, ix0 = (int)flx0;
        int iy1 = (int)fly1, ix1 = (int)flx1;

        float a0 = 0.f, a1 = 0.f, a2 = 0.f;
        float b0 = 0.f, b1 = 0.f, b2 = 0.f;

        bool ok = (iy0 >= 1) & (iy0 <= H - 5) & (ix0 >= 1) & (ix0 <= W - 3) &
                  (iy1 == iy0 + 1) & (ix1 == ix0);

        if (ok) {
            // union window: 5 rows x 12 floats, 15 float4 loads for 2 px
            int off = ((iy0 - 1) * W + (ix0 - 1)) * 3;
            const float* p0 = img + off;
            const float* p1 = p0 + RS;
            const float* p2 = p1 + RS;
            const float* p3 = p2 + RS;
            const float* p4 = p3 + RS;
            float4 v0a = ((const float4*)p0)[0], v0b = ((const float4*)p0)[1], v0c = ((const float4*)p0)[2];
            float4 v1a = ((const float4*)p1)[0], v1b = ((const float4*)p1)[1], v1c = ((const float4*)p1)[2];
            float4 v2a = ((const float4*)p2)[0], v2b = ((const float4*)p2)[1], v2c = ((const float4*)p2)[2];
            float4 v3a = ((const float4*)p3)[0], v3b = ((const float4*)p3)[1], v3c = ((const float4*)p3)[2];
            float4 v4a = ((const float4*)p4)[0], v4b = ((const float4*)p4)[1], v4c = ((const float4*)p4)[2];

            float wyA0 = k_outer(1.f + fy0), wyA1 = k_inner(fy0), wyA2 = k_inner(1.f - fy0), wyA3 = k_outer(2.f - fy0);
            float wxA0 = k_outer(1.f + fx0), wxA1 = k_inner(fx0), wxA2 = k_inner(1.f - fx0), wxA3 = k_outer(2.f - fx0);
            float wyB0 = k_outer(1.f + fy1), wyB1 = k_inner(fy1), wyB2 = k_inner(1.f - fy1), wyB3 = k_outer(2.f - fy1);
            float wxB0 = k_outer(1.f + fx1), wxB1 = k_inner(fx1), wxB2 = k_inner(1.f - fx1), wxB3 = k_outer(2.f - fx1);

            float t0, t1, t2;
            // px0: union rows 0..3
            ROWDOT(v0a, v0b, v0c, wxA0, wxA1, wxA2, wxA3, t0, t1, t2)
            a0 = wyA0 * t0; a1 = wyA0 * t1; a2 = wyA0 * t2;
            ROWDOT(v1a, v1b, v1c, wxA0, wxA1, wxA2, wxA3, t0, t1, t2)
            a0 = fmaf(wyA1, t0, a0); a1 = fmaf(wyA1, t1, a1); a2 = fmaf(wyA1, t2, a2);
            ROWDOT(v2a, v2b, v2c, wxA0, wxA1, wxA2, wxA3, t0, t1, t2)
            a0 = fmaf(wyA2, t0, a0); a1 = fmaf(wyA2, t1, a1); a2 = fmaf(wyA2, t2, a2);
            ROWDOT(v3a, v3b, v3c, wxA0, wxA1, wxA2, wxA3, t0, t1, t2)
            a0 = fmaf(wyA3, t0, a0); a1 = fmaf(wyA3, t1, a1); a2 = fmaf(wyA3, t2, a2);
            // px1: union rows 1..4
            ROWDOT(v1a, v1b, v1c, wxB0, wxB1, wxB2, wxB3, t0, t1, t2)
            b0 = wyB0 * t0; b1 = wyB0 * t1; b2 = wyB0 * t2;
            ROWDOT(v2a, v2b, v2c, wxB0, wxB1, wxB2, wxB3, t0, t1, t2)
            b0 = fmaf(wyB1, t0, b0); b1 = fmaf(wyB1, t1, b1); b2 = fmaf(wyB1, t2, b2);
            ROWDOT(v3a, v3b, v3c, wxB0, wxB1, wxB2, wxB3, t0, t1, t2)
            b0 = fmaf(wyB2, t0, b0); b1 = fmaf(wyB2, t1, b1); b2 = fmaf(wyB2, t2, b2);
            ROWDOT(v4a, v4b, v4c, wxB0, wxB1, wxB2, wxB3, t0, t1, t2)
            b0 = fmaf(wyB3, t0, b0); b1 = fmaf(wyB3, t1, b1); b2 = fmaf(wyB3, t2, b2);
        }
        if (!ok) {
            // exec-masked rare-lane patch (~1% lanes; skipped via execz in clean waves)
            gather_px(img, iy0, ix0, fy0, fx0, a0, a1, a2);
            gather_px(img, iy1, ix1, fy1, fx1, b0, b1, b2);
        }

        int oo = rowbase0 + w * 3;
        __builtin_nontemporal_store(a0, out + oo);
        __builtin_nontemporal_store(a1, out + oo + 1);
        __builtin_nontemporal_store(a2, out + oo + 2);
        __builtin_nontemporal_store(b0, out + oo + RS);
        __builtin_nontemporal_store(b1, out + oo + RS + 1);
        __builtin_nontemporal_store(b2, out + oo + RS + 2);
    }
}

extern "C" void kernel_launch(void* const* d_in, const int* in_sizes, int n_in,
                              void* d_out, int out_size, void* d_ws, size_t ws_size,
                              hipStream_t stream) {
    const float* img   = (const float*)d_in[0];
    const float* dctrl = (const float*)d_in[1];
    float* out = (float*)d_out;

    dim3 grid(W / 64, H / 32);   // 64x32 px per block
    elastic_warp_kernel<<<grid, 256, 0, stream>>>(img, dctrl, out);
}

// Round 14
// 61.657 us; speedup vs baseline: 2.6531x; 2.6531x over previous
//
#include <hip/hip_runtime.h>
#include <math.h>

constexpr int H = 2048;
constexpr int W = 4096;
constexpr int RS = W * 3;   // floats per image row

typedef __attribute__((ext_vector_type(2))) float f32x2;

__device__ __forceinline__ f32x2 pk(float a, float b) { f32x2 r; r.x = a; r.y = b; return r; }
__device__ __forceinline__ f32x2 splat(float a) { f32x2 r; r.x = a; r.y = a; return r; }
__device__ __forceinline__ f32x2 pfma(f32x2 a, f32x2 b, f32x2 c) {
    return __builtin_elementwise_fma(a, b, c);
}

// Keys cubic (a = -0.5) pieces on known-positive argument — scalar and packed.
__device__ __forceinline__ float k_inner(float t) {   // t in [0,1]:  1.5t^3 - 2.5t^2 + 1
    return fmaf(fmaf(1.5f, t, -2.5f), t * t, 1.0f);
}
__device__ __forceinline__ float k_outer(float t) {   // t in [1,2]: -0.5t^3 + 2.5t^2 - 4t + 2
    return fmaf(fmaf(fmaf(-0.5f, t, 2.5f), t, -4.0f), t, 2.0f);
}
__device__ __forceinline__ f32x2 k_inner2(f32x2 t) {
    f32x2 a = pfma(splat(1.5f), t, splat(-2.5f));
    return pfma(a, t * t, splat(1.0f));
}
__device__ __forceinline__ f32x2 k_outer2(f32x2 t) {
    f32x2 a = pfma(splat(-0.5f), t, splat(2.5f));
    a = pfma(a, t, splat(-4.0f));
    return pfma(a, t, splat(2.0f));
}
__device__ __forceinline__ float cubic_w(float t) {
    float at = fabsf(t);
    if (at <= 1.0f) return k_inner(at);
    if (at < 2.0f)  return k_outer(at);
    return 0.0f;
}

// packed RG row dot from one 12-float row (va,vb,vc), B scalar
#define ROWDOT_PK(va, vb, vc, wxv0, wxv1, wxv2, wxv3, wx0s, wx1s, wx2s, wx3s, TRG, TB)        \
    {   f32x2 rg0 = pk(va.x, va.y), rg1 = pk(va.w, vb.x), rg2 = pk(vb.z, vb.w), rg3 = pk(vc.y, vc.z); \
        TRG = pfma(wxv0, rg0, pfma(wxv1, rg1, pfma(wxv2, rg2, wxv3 * rg3)));                   \
        TB  = fmaf(wx0s, va.z, fmaf(wx1s, vb.y, fmaf(wx2s, vc.x, wx3s * vc.w))); }

// Block covers a 64x16 px region = 4 tiles of 16x16, processed in a loop.
// Wave lane layout: xi = lane&15 (column), gi = lane>>4; row r = wave*4 + gi.
__global__ __launch_bounds__(256)
void elastic_warp_kernel(const float* __restrict__ img,
                         const float* __restrict__ dctrl,  // (2,3,3) unscaled
                         float* __restrict__ out) {
    int x0r = blockIdx.x << 6;    // 64-px x-region
    int y0  = blockIdx.y << 4;    // 16-px y-band

    int t = threadIdx.x;
    int lane = t & 63;
    int wave = t >> 6;
    int xi = lane & 15;
    int gi = lane >> 4;
    int r  = (wave << 2) + gi;    // row within band, 0..15

    // ---- per-band-row uniform: cy = 5 * (by^T . D), 16 rows, computed once ----
    __shared__ float s_cy[16][6];
    if (t < 16) {
        int hh = y0 + t;
        float u = (float)(2 * hh) / (float)(H - 1);
        float i0 = floorf(u);
        float by0 = 0.f, by1 = 0.f, by2 = 0.f;
#pragma unroll
        for (int k = -1; k < 3; ++k) {
            float tap = i0 + (float)k;
            float wt = cubic_w(u - tap);
            int tc = (int)tap;
            tc = tc < 0 ? 0 : (tc > 2 ? 2 : tc);
            if (tc == 0) by0 += wt; else if (tc == 1) by1 += wt; else by2 += wt;
        }
#pragma unroll
        for (int x = 0; x < 3; ++x) {
            s_cy[t][x]     = 5.0f * (by0 * dctrl[x]     + by1 * dctrl[3 + x]  + by2 * dctrl[6 + x]);
            s_cy[t][3 + x] = 5.0f * (by0 * dctrl[9 + x] + by1 * dctrl[12 + x] + by2 * dctrl[15 + x]);
        }
    }
    __syncthreads();

    // hoisted per-thread invariants (same image row for all 4 tiles)
    int h = y0 + r;
    float hf = (float)h;
    float cy0 = s_cy[r][0], cy1 = s_cy[r][1], cy2 = s_cy[r][2];
    float cy3 = s_cy[r][3], cy4 = s_cy[r][4], cy5 = s_cy[r][5];
    int rowbase = h * W;

#pragma unroll
    for (int it = 0; it < 4; ++it) {
        int w = x0r + (it << 4) + xi;

        // ---- per-px spline bx (piecewise, packed evals) ----
        float u = (float)w * (2.0f / 4095.0f);
        bool hiu = u >= 1.0f;
        float s = u - (hiu ? 1.0f : 0.0f);
        f32x2 eo = k_outer2(pk(1.0f + s, 2.0f - s));   // {o1, o2}
        f32x2 ei = k_inner2(pk(s, 1.0f - s));          // {is, i1}
        float o1 = eo.x, o2 = eo.y, is = ei.x, i1 = ei.y;
        float bx0 = hiu ? o1 : (o1 + is);
        float bx1 = hiu ? is : i1;
        float bx2 = hiu ? (i1 + o2) : o2;

        float d0 = cy0 * bx0 + cy1 * bx1 + cy2 * bx2;
        float d1 = cy3 * bx0 + cy4 * bx1 + cy5 * bx2;

        // ---- sample coordinates ----
        float yy = hf + d0;
        float xx = (float)w + d1;
        float iy0f = floorf(yy);
        float ix0f = floorf(xx);
        float fy = yy - iy0f;
        float fx = xx - ix0f;
        int iy0 = (int)iy0f;
        int ix0 = (int)ix0f;

        // ---- packed tap-weight evals: {wy_i, wx_i} pairs ----
        f32x2 w0p = k_outer2(pk(1.0f + fy, 1.0f + fx));   // {wy0, wx0}
        f32x2 w1p = k_inner2(pk(fy, fx));                 // {wy1, wx1}
        f32x2 w2p = k_inner2(pk(1.0f - fy, 1.0f - fx));   // {wy2, wx2}
        f32x2 w3p = k_outer2(pk(2.0f - fy, 2.0f - fx));   // {wy3, wx3}
        float wy0 = w0p.x, wx0 = w0p.y;
        float wy1 = w1p.x, wx1 = w1p.y;
        float wy2 = w2p.x, wx2 = w2p.y;
        float wy3 = w3p.x, wx3 = w3p.y;

        float acc0, acc1, acc2;

        bool interior = (iy0 >= 1) & (iy0 <= H - 3) & (ix0 >= 1) & (ix0 <= W - 3);
        if (interior) {
            int off = ((iy0 - 1) * W + (ix0 - 1)) * 3;
            const float* b0 = img + off;
            const float* b1 = b0 + RS;
            const float* b2 = b1 + RS;
            const float* b3 = b2 + RS;

            float4 v00 = ((const float4*)b0)[0];
            float4 v01 = ((const float4*)b0)[1];
            float4 v02 = ((const float4*)b0)[2];
            float4 v10 = ((const float4*)b1)[0];
            float4 v11 = ((const float4*)b1)[1];
            float4 v12 = ((const float4*)b1)[2];
            float4 v20 = ((const float4*)b2)[0];
            float4 v21 = ((const float4*)b2)[1];
            float4 v22 = ((const float4*)b2)[2];
            float4 v30 = ((const float4*)b3)[0];
            float4 v31 = ((const float4*)b3)[1];
            float4 v32 = ((const float4*)b3)[2];

            f32x2 wxv0 = splat(wx0), wxv1 = splat(wx1), wxv2 = splat(wx2), wxv3 = splat(wx3);

            f32x2 t0rg, t1rg, t2rg, t3rg;
            float t0b, t1b, t2b, t3b;
            ROWDOT_PK(v00, v01, v02, wxv0, wxv1, wxv2, wxv3, wx0, wx1, wx2, wx3, t0rg, t0b)
            ROWDOT_PK(v10, v11, v12, wxv0, wxv1, wxv2, wxv3, wx0, wx1, wx2, wx3, t1rg, t1b)
            ROWDOT_PK(v20, v21, v22, wxv0, wxv1, wxv2, wxv3, wx0, wx1, wx2, wx3, t2rg, t2b)
            ROWDOT_PK(v30, v31, v32, wxv0, wxv1, wxv2, wxv3, wx0, wx1, wx2, wx3, t3rg, t3b)

            f32x2 accRG = pfma(splat(wy0), t0rg,
                          pfma(splat(wy1), t1rg,
                          pfma(splat(wy2), t2rg, splat(wy3) * t3rg)));
            acc2 = fmaf(wy0, t0b, fmaf(wy1, t1b, fmaf(wy2, t2b, wy3 * t3b)));
            acc0 = accRG.x;
            acc1 = accRG.y;
        } else {
            acc0 = 0.f; acc1 = 0.f; acc2 = 0.f;
            float wy[4] = {wy0, wy1, wy2, wy3};
            float wx[4] = {wx0, wx1, wx2, wx3};
#pragma unroll
            for (int a = 0; a < 4; ++a) {
                int ty = iy0 + a - 1;
                ty = ty < 0 ? 0 : (ty > H - 1 ? H - 1 : ty);
                int rowoff = ty * RS;
                float ay = wy[a];
#pragma unroll
                for (int b = 0; b < 4; ++b) {
                    int tx = ix0 + b - 1;
                    tx = tx < 0 ? 0 : (tx > W - 1 ? W - 1 : tx);
                    float wgt = ay * wx[b];
                    const float* p = img + rowoff + tx * 3;
                    acc0 += wgt * p[0];
                    acc1 += wgt * p[1];
                    acc2 += wgt * p[2];
                }
            }
        }

        int oo = (rowbase + w) * 3;
        __builtin_nontemporal_store(acc0, out + oo);
        __builtin_nontemporal_store(acc1, out + oo + 1);
        __builtin_nontemporal_store(acc2, out + oo + 2);
    }
}

extern "C" void kernel_launch(void* const* d_in, const int* in_sizes, int n_in,
                              void* d_out, int out_size, void* d_ws, size_t ws_size,
                              hipStream_t stream) {
    const float* img   = (const float*)d_in[0];
    const float* dctrl = (const float*)d_in[1];
    float* out = (float*)d_out;

    dim3 grid(W / 64, H / 16);   // 64x16 px per block
    elastic_warp_kernel<<<grid, 256, 0, stream>>>(img, dctrl, out);
}